// Round 5
// baseline (1272.632 us; speedup 1.0000x reference)
//
#include <hip/hip_runtime.h>
#include <hip/hip_cooperative_groups.h>
#include <cstdint>

namespace cg = cooperative_groups;

#define NNODES 50000
#define NEDGES 800000
#define ETOT   (NEDGES + NNODES)
#define HEADS 4
#define CH 64
#define HC 256
#define INDIM 256
#define OUTDIM 64
#define NEG_SLOPE 0.2f
#define BN_EPS 1e-5f
#define NB 128          // bn_stats partial blocks
#define CSR_BLOCKS 1024
#define CSR_GSZ (CSR_BLOCKS * 256)   // 262144 threads

typedef unsigned short u16;
typedef unsigned int u32;
typedef __attribute__((ext_vector_type(8))) short short8;
typedef __attribute__((ext_vector_type(8))) unsigned short ushort8v;
typedef __attribute__((ext_vector_type(4))) float floatx4;

__device__ inline float bf2f(u16 u) {
    union { unsigned int i; float f; } c;
    c.i = ((unsigned int)u) << 16;
    return c.f;
}
__device__ inline u16 f2bf(float f) {
    union { float f; unsigned int i; } c;
    c.f = f;
    unsigned int u = c.i + 0x7fff + ((c.i >> 16) & 1);
    return (u16)(u >> 16);
}
// permuted position of logical channel b (within-head 16x4 transpose)
__device__ __host__ inline int pos256(int b) {
    int h = b >> 6, c = b & 63;
    return h * 64 + (c & 15) * 4 + (c >> 4);
}
__device__ inline void async16(u16* lds, const u16* g) {
    __builtin_amdgcn_global_load_lds(
        (const __attribute__((address_space(1))) unsigned int*)g,
        (__attribute__((address_space(3))) unsigned int*)lds,
        16, 0, 0);
}
// device-coherent loads: bypass possibly-stale clean lines in per-XCD L2
// (needed for cross-phase reads inside cooperative kernels; no dispatch-
// boundary cache invalidation happens between grid.sync phases)
__device__ inline int ld_devi(const int* p) {
    return __hip_atomic_load(p, __ATOMIC_RELAXED, __HIP_MEMORY_SCOPE_AGENT);
}
__device__ inline float ld_devf(const float* p) {
    return __hip_atomic_load(p, __ATOMIC_RELAXED, __HIP_MEMORY_SCOPE_AGENT);
}

// ---------------- fused CSR build + W1 cast (cooperative, 5 phases) ----------------
// P0: zero cnt + cast W1 -> w1t   | P1: histogram of dst degrees
// P2: per-4096-chunk exclusive scan (blocks 0..12) | P3: chunk-prefix add, write nxt
// P4: fill csr_src (dst-sorted src list) via per-node atomic cursors

#define FILL_S (ETOT / 4)   // 212500, exact

__global__ __launch_bounds__(256)
void csr_build_kernel(const int* __restrict__ ei, int* __restrict__ cnt,
                      int* __restrict__ row_off, int* __restrict__ nxt,
                      int* __restrict__ bsums, int* __restrict__ csr_src,
                      const float* __restrict__ W1, u16* __restrict__ w1t) {
    cg::grid_group grid = cg::this_grid();
    const int tid = threadIdx.x;
    const int gt = blockIdx.x * 256 + tid;
    __shared__ int tsum[256];
    __shared__ int sprefix;

    // ---- P0: zero counters + weight cast (independent work) ----
    for (int i = gt; i < NNODES; i += CSR_GSZ) cnt[i] = 0;
    for (int i = gt; i < INDIM * HC; i += CSR_GSZ) {
        int k = i >> 8, n = i & 255;          // Ncols = HC = 256
        w1t[n * INDIM + k] = f2bf(W1[i]);
    }
    __threadfence();
    grid.sync();

    // ---- P1: histogram ----
    for (int t = gt; t < ETOT; t += CSR_GSZ) {
        int d = (t < NEDGES) ? ei[NEDGES + t] : (t - NEDGES);
        atomicAdd(&cnt[d], 1);
    }
    __threadfence();
    grid.sync();

    // ---- P2: per-chunk scan (blocks 0..scanBlocks-1) ----
    const int scanBlocks = (NNODES + 4095) / 4096;   // 13
    if ((int)blockIdx.x < scanBlocks) {
        const int base = blockIdx.x * 4096 + tid * 16;
        int local[16];
        int run = 0;
#pragma unroll
        for (int i = 0; i < 16; ++i) {
            int idx = base + i;
            int v = (idx < NNODES) ? ld_devi(&cnt[idx]) : 0;
            local[i] = run;
            run += v;
        }
        tsum[tid] = run;
        __syncthreads();
        for (int dd = 1; dd < 256; dd <<= 1) {
            int v = (tid >= dd) ? tsum[tid - dd] : 0;
            __syncthreads();
            tsum[tid] += v;
            __syncthreads();
        }
        int excl = (tid == 0) ? 0 : tsum[tid - 1];
#pragma unroll
        for (int i = 0; i < 16; ++i) {
            int idx = base + i;
            if (idx < NNODES) row_off[idx] = excl + local[i];
        }
        if (tid == 0) bsums[blockIdx.x] = tsum[255];
    }
    __threadfence();
    grid.sync();

    // ---- P3: add chunk prefix, write final row_off + nxt ----
    if ((int)blockIdx.x < scanBlocks) {
        if (tid == 0) {
            int p = 0;
            for (int b = 0; b < (int)blockIdx.x; ++b) p += ld_devi(&bsums[b]);
            sprefix = p;
        }
        __syncthreads();
        int prefix = sprefix;
        int base = blockIdx.x * 4096 + tid * 16;
#pragma unroll
        for (int i = 0; i < 16; ++i) {
            int idx = base + i;
            if (idx < NNODES) {
                int v = row_off[idx] + prefix;   // own block's P2 write (same L2)
                row_off[idx] = v;
                nxt[idx] = v;
            }
        }
        if (blockIdx.x == 0 && tid == 0) row_off[NNODES] = ETOT;
    }
    __threadfence();
    grid.sync();

    // ---- P4: fill (4 edges/thread, independent atomic->store chains) ----
    if (gt < FILL_S) {
        int s[4], d[4], p[4];
#pragma unroll
        for (int k = 0; k < 4; ++k) {
            int e = gt + k * FILL_S;
            if (e < NEDGES) { s[k] = ei[e]; d[k] = ei[NEDGES + e]; }
            else            { s[k] = d[k] = e - NEDGES; }
        }
#pragma unroll
        for (int k = 0; k < 4; ++k) p[k] = atomicAdd(&nxt[d[k]], 1);
#pragma unroll
        for (int k = 0; k < 4; ++k) csr_src[p[k]] = s[k];
    }
}

// ---------------- bf16 MFMA GEMM + fused alpha + permuted bf16 output ----------------

template <bool AF32>
__global__ __launch_bounds__(256)
void gemm_gat_kernel(const void* __restrict__ Ap, const u16* __restrict__ Bt,
                     const float* __restrict__ bias,
                     const float* __restrict__ att_s, const float* __restrict__ att_d,
                     u16* __restrict__ xhp, float* __restrict__ asrc,
                     float* __restrict__ adst, int M, int K) {
    __shared__ u16 As[128 * 32];
    __shared__ u16 Bs[128 * 32];
    const int tid = threadIdx.x;
    const int wave = tid >> 6, lane = tid & 63;
    const int q15 = lane & 15, quad = lane >> 4;
    const int rowBase = blockIdx.y * 128;
    const int colBase = blockIdx.x * 128;
    const int waveM = (wave >> 1) * 64, waveN = (wave & 1) * 64;
    const int head = blockIdx.x * 2 + (wave & 1);

    floatx4 acc[4][4];
    floatx4 zero = {0.f, 0.f, 0.f, 0.f};
#pragma unroll
    for (int i = 0; i < 4; ++i)
#pragma unroll
        for (int j = 0; j < 4; ++j) acc[i][j] = zero;

    for (int kt = 0; kt < K; kt += 32) {
        if constexpr (AF32) {
            const float* A32 = (const float*)Ap;
#pragma unroll
            for (int rnd = 0; rnd < 4; ++rnd) {
                int slot = rnd * 256 + tid;
                int r = slot >> 3, c4 = (slot & 7) * 4;
                int ar = rowBase + r; if (ar >= M) ar = M - 1;
                float4 fv = *(const float4*)&A32[(size_t)ar * K + kt + c4];
                ushort4 o;
                o.x = f2bf(fv.x); o.y = f2bf(fv.y); o.z = f2bf(fv.z); o.w = f2bf(fv.w);
                *(ushort4*)&As[r * 32 + c4] = o;
            }
#pragma unroll
            for (int q = 0; q < 2; ++q) {
                int e8 = (wave * 2 + q) * 64 + lane;
                int r = e8 >> 2, c = (e8 & 3) * 8;
                async16(&Bs[(wave * 2 + q) * 512], &Bt[(size_t)(colBase + r) * K + kt + c]);
            }
        } else {
            const u16* A16 = (const u16*)Ap;
#pragma unroll
            for (int q = 0; q < 2; ++q) {
                int e8 = (wave * 2 + q) * 64 + lane;
                int r = e8 >> 2, c = (e8 & 3) * 8;
                int ar = rowBase + r; if (ar >= M) ar = M - 1;
                async16(&As[(wave * 2 + q) * 512], &A16[(size_t)ar * K + kt + c]);
                async16(&Bs[(wave * 2 + q) * 512], &Bt[(size_t)(colBase + r) * K + kt + c]);
            }
        }
        __syncthreads();

        short8 af[4], bfr[4];
#pragma unroll
        for (int i = 0; i < 4; ++i)
            af[i] = *(const short8*)&As[(waveM + i * 16 + q15) * 32 + quad * 8];
#pragma unroll
        for (int j = 0; j < 4; ++j)
            bfr[j] = *(const short8*)&Bs[(waveN + j * 16 + q15) * 32 + quad * 8];
#pragma unroll
        for (int i = 0; i < 4; ++i)
#pragma unroll
            for (int j = 0; j < 4; ++j)
                acc[i][j] = __builtin_amdgcn_mfma_f32_16x16x32_bf16(af[i], bfr[j], acc[i][j], 0, 0, 0);
        __syncthreads();
    }

    float bv[4], atsv[4], atdv[4];
#pragma unroll
    for (int j = 0; j < 4; ++j) {
        int gcol = colBase + waveN + j * 16 + q15;
        bv[j] = bias ? bias[gcol] : 0.f;
        int hc = head * CH + j * 16 + q15;
        atsv[j] = att_s[hc];
        atdv[j] = att_d[hc];
    }
    const int pbase = head * 64 + q15 * 4;

#pragma unroll
    for (int i = 0; i < 4; ++i) {
#pragma unroll
        for (int rr = 0; rr < 4; ++rr) {
            int grow = rowBase + waveM + i * 16 + quad * 4 + rr;
            float v[4];
#pragma unroll
            for (int j = 0; j < 4; ++j) v[j] = acc[i][j][rr] + bv[j];
            float s = v[0] * atsv[0] + v[1] * atsv[1] + v[2] * atsv[2] + v[3] * atsv[3];
            float d = v[0] * atdv[0] + v[1] * atdv[1] + v[2] * atdv[2] + v[3] * atdv[3];
#pragma unroll
            for (int off = 1; off <= 8; off <<= 1) {
                s += __shfl_xor(s, off, 64);
                d += __shfl_xor(d, off, 64);
            }
            ushort4 o;
            o.x = f2bf(v[0]); o.y = f2bf(v[1]); o.z = f2bf(v[2]); o.w = f2bf(v[3]);
            if (grow < M) {
                *(ushort4*)&xhp[(size_t)grow * HC + pbase] = o;
                if (q15 == 0) {
                    asrc[grow * 4 + head] = s;
                    adst[grow * 4 + head] = d;
                }
            }
        }
    }
}

// ---------------- fused softmax+aggregate over permuted bf16 table ----------------
// 1 wave = 1 dst node (proven structure; at the random-512B-gather fabric
// ceiling ~3.7 TB/s). Per 64-edge batch: per-wave LDS table of exp-weights +
// src; main loop reads 2 edges per dwordx4 gather, unrolled to 8 edges.

__global__ __launch_bounds__(256)
void aggregate_kernel(const int* __restrict__ row_off, const int* __restrict__ csr_src,
                      const float* __restrict__ asrc, const float* __restrict__ adst,
                      const u16* __restrict__ xhp, const float* __restrict__ bias,
                      u16* __restrict__ out) {
    __shared__ int eb[4][512];          // per wave: 64 edges x {w0..w3 (f32), sv, pad3}
    const int g = threadIdx.x >> 6;
    const int lane = threadIdx.x & 63;
    const int d = blockIdx.x * 4 + g;
    const int eh = lane >> 5;            // which edge of a pair this lane serves
    const int L = lane & 31;
    const int h = L >> 3;                // head
    const int g8 = L & 7;                // 8-position group within head
    const u32 pb = (u32)(h * 128 + g8 * 16);   // byte offset within row (16B aligned)
    int* my = &eb[g][0];

    const int start = row_off[d], end = row_off[d + 1];
    const float4 ad4 = *(const float4*)&adst[d * 4];   // wave-uniform
    float acc[8] = {0.f, 0.f, 0.f, 0.f, 0.f, 0.f, 0.f, 0.f};
    float den = 0.f;

#define ACC4(W, Q, J0) { u32 dw_ = (u32)(Q); \
        acc[J0]     += (W) * __int_as_float(dw_ << 16); \
        acc[(J0)+1] += (W) * __int_as_float(dw_ & 0xffff0000u); }

    for (int base = start; base < end; base += 64) {
        const int cnt = min(64, end - base);
        int4 pack = {0, 0, 0, 0};
        int svv = 0;
        if (lane < cnt) {
            svv = csr_src[base + lane];
            float4 as4 = *(const float4*)&asrc[svv * 4];
            float e0 = as4.x + ad4.x; e0 = e0 > 0.f ? e0 : NEG_SLOPE * e0;
            float e1 = as4.y + ad4.y; e1 = e1 > 0.f ? e1 : NEG_SLOPE * e1;
            float e2 = as4.z + ad4.z; e2 = e2 > 0.f ? e2 : NEG_SLOPE * e2;
            float e3 = as4.w + ad4.w; e3 = e3 > 0.f ? e3 : NEG_SLOPE * e3;
            pack.x = __float_as_int(__expf(e0));
            pack.y = __float_as_int(__expf(e1));
            pack.z = __float_as_int(__expf(e2));
            pack.w = __float_as_int(__expf(e3));
        }
        *(int4*)&my[lane * 8] = pack;    // zeroed beyond cnt -> safe padding
        my[lane * 8 + 4] = svv;
        // cross-lane LDS RAW within the wave: drain before pair reads.
        asm volatile("s_waitcnt lgkmcnt(0)" ::: "memory");
        __builtin_amdgcn_sched_barrier(0);

        const int cntp = (cnt + 1) & ~1;  // pad to even; padded edge has w=0
        int k = 0;
        for (; k + 7 < cntp; k += 8) {
            float wv[4]; int sa[4];
#pragma unroll
            for (int p = 0; p < 4; ++p) {
                int idx = (k + 2 * p + eh) * 8;
                wv[p] = __int_as_float(my[idx + h]);
                sa[p] = my[idx + 4];
            }
            int4 gv[4];
#pragma unroll
            for (int p = 0; p < 4; ++p) {
                u32 off = ((u32)sa[p] << 9) + pb;
                gv[p] = *(const int4*)((const char*)xhp + off);
            }
#pragma unroll
            for (int p = 0; p < 4; ++p) {
                float w = wv[p];
                den += w;
                ACC4(w, gv[p].x, 0); ACC4(w, gv[p].y, 2);
                ACC4(w, gv[p].z, 4); ACC4(w, gv[p].w, 6);
            }
        }
        for (; k < cntp; k += 2) {
            int idx = (k + eh) * 8;
            float w = __int_as_float(my[idx + h]);
            int s = my[idx + 4];
            u32 off = ((u32)s << 9) + pb;
            int4 gvv = *(const int4*)((const char*)xhp + off);
            den += w;
            ACC4(w, gvv.x, 0); ACC4(w, gvv.y, 2);
            ACC4(w, gvv.z, 4); ACC4(w, gvv.w, 6);
        }
    }
#undef ACC4

#pragma unroll
    for (int i = 0; i < 8; ++i) acc[i] += __shfl_xor(acc[i], 32, 64);
    den += __shfl_xor(den, 32, 64);

    if (eh == 0) {
        float inv = 1.f / (den + 1e-16f);
        const int cb = h * 64 + g8 * 2;   // logical channel base for j=0
        ushort8v o;
#pragma unroll
        for (int j = 0; j < 8; ++j)
            o[j] = f2bf(acc[j] * inv + bias[cb + (j >> 2) + (j & 3) * 16]);
        *(ushort8v*)&out[(size_t)d * HC + h * 64 + g8 * 8] = o;   // permuted, coalesced
    }
}

// ---------------- fused BN stats + fold (cooperative, 2 phases) ----------------
// P0 (blocks 0..NB-1): partial sums/sumsq over permuted buffer -> part
// P1 (all 257 blocks): blocks 0..255 fold BN into Wt columns; block 256
// computes the folded bias vector. part reads use device-coherent loads.

__global__ __launch_bounds__(256)
void statsfold_kernel(const u16* __restrict__ x, float* __restrict__ part,
                      const float* __restrict__ W, const float* __restrict__ g,
                      const float* __restrict__ beta, const float* __restrict__ baseBias,
                      u16* __restrict__ Wt, float* __restrict__ biasOut, int Ncols) {
    cg::grid_group grid = cg::this_grid();
    const int tid = threadIdx.x;
    __shared__ float red[4][512];
    __shared__ float sh[256];
    __shared__ float stat2[2];

    // ---- P0: stats ----
    if (blockIdx.x < NB) {
        float s[8] = {}, s2[8] = {};
        const size_t total = (size_t)NNODES * HC;
        const size_t stride = (size_t)NB * 256 * 8;
        for (size_t f = ((size_t)blockIdx.x * 256 + tid) * 8; f < total; f += stride) {
            ushort8v v = *(const ushort8v*)&x[f];
#pragma unroll
            for (int i = 0; i < 8; ++i) {
                float t = bf2f(v[i]);
                s[i] += t;
                s2[i] += t * t;
            }
        }
#pragma unroll
        for (int i = 0; i < 8; ++i) {
            s[i] += __shfl_xor(s[i], 32, 64);
            s2[i] += __shfl_xor(s2[i], 32, 64);
        }
        const int wave = tid >> 6, lane = tid & 63;
        if (lane < 32) {
#pragma unroll
            for (int i = 0; i < 8; ++i) {
                red[wave][lane * 8 + i] = s[i];
                red[wave][256 + lane * 8 + i] = s2[i];
            }
        }
        __syncthreads();
        for (int j = tid; j < 512; j += 256)
            part[(size_t)blockIdx.x * 512 + j] = red[0][j] + red[1][j] + red[2][j] + red[3][j];
    }
    __threadfence();
    grid.sync();

    // ---- P1: fold ----
    const int b = blockIdx.x;
    if (b < 256) {
        const int p = pos256(b);
        const int wave = tid >> 6, lane = tid & 63;
        if (wave < 2) {
            int off = wave * 256;
            float v = ld_devf(&part[(size_t)lane * 512 + off + p]) +
                      ld_devf(&part[(size_t)(lane + 64) * 512 + off + p]);
#pragma unroll
            for (int o = 1; o <= 32; o <<= 1) v += __shfl_xor(v, o, 64);
            if (lane == 0) stat2[wave] = v;
        }
        __syncthreads();
        float mu = stat2[0] * (1.f / NNODES);
        float var = stat2[1] * (1.f / NNODES) - mu * mu;
        float rg = rsqrtf(var + BN_EPS) * g[b];
        for (int n = tid; n < Ncols; n += 256)
            Wt[n * 256 + p] = f2bf(W[b * Ncols + n] * rg);
    } else {
        const int p = pos256(tid);
        float sum = 0.f, sq = 0.f;
        for (int k = 0; k < NB; ++k) {
            sum += ld_devf(&part[(size_t)k * 512 + p]);
            sq += ld_devf(&part[(size_t)k * 512 + 256 + p]);
        }
        float mu = sum * (1.f / NNODES);
        float var = sq * (1.f / NNODES) - mu * mu;
        float rg = rsqrtf(var + BN_EPS) * g[tid];
        sh[tid] = beta[tid] - mu * rg;
        __syncthreads();
        if (tid < Ncols) {
            float acc = baseBias ? baseBias[tid] : 0.f;
            for (int k = 0; k < 256; ++k) acc += sh[k] * W[k * Ncols + tid];
            biasOut[tid] = acc;
        }
    }
}

// ---------------- fused final GEMM (M x 64, K=256) + bias + log_softmax ----------------

__global__ __launch_bounds__(256)
void final_ls_kernel(const u16* __restrict__ A, const u16* __restrict__ Bt,
                     const float* __restrict__ bias,
                     float* __restrict__ emb, float* __restrict__ out, int M) {
    __shared__ u16 As[128 * 32];
    __shared__ u16 Bs[64 * 32];
    const int tid = threadIdx.x;
    const int wave = tid >> 6, lane = tid & 63;
    const int q15 = lane & 15, quad = lane >> 4;
    const int rowBase = blockIdx.x * 128;

    floatx4 acc[2][4];
    floatx4 zero = {0.f, 0.f, 0.f, 0.f};
#pragma unroll
    for (int i = 0; i < 2; ++i)
#pragma unroll
        for (int j = 0; j < 4; ++j) acc[i][j] = zero;

    for (int kt = 0; kt < 256; kt += 32) {
#pragma unroll
        for (int rnd = 0; rnd < 2; ++rnd) {
            int slot = rnd * 256 + wave * 64 + lane;
            int r = slot >> 2;
            int c = (slot & 3) * 8;
            int ar = rowBase + r; if (ar >= M) ar = M - 1;
            async16(&As[(rnd * 256 + wave * 64) * 8], &A[(size_t)ar * 256 + kt + c]);
        }
        {
            int slot = wave * 64 + lane;
            int r = slot >> 2;
            int c = (slot & 3) * 8;
            async16(&Bs[(wave * 64) * 8], &Bt[(size_t)r * 256 + kt + c]);
        }
        __syncthreads();

        short8 af[2], bfr[4];
#pragma unroll
        for (int i = 0; i < 2; ++i)
            af[i] = *(const short8*)&As[(wave * 32 + i * 16 + q15) * 32 + quad * 8];
#pragma unroll
        for (int j = 0; j < 4; ++j)
            bfr[j] = *(const short8*)&Bs[(j * 16 + q15) * 32 + quad * 8];
#pragma unroll
        for (int i = 0; i < 2; ++i)
#pragma unroll
            for (int j = 0; j < 4; ++j)
                acc[i][j] = __builtin_amdgcn_mfma_f32_16x16x32_bf16(af[i], bfr[j], acc[i][j], 0, 0, 0);
        __syncthreads();
    }

#pragma unroll
    for (int i = 0; i < 2; ++i) {
#pragma unroll
        for (int rr = 0; rr < 4; ++rr) {
            float v[4];
#pragma unroll
            for (int j = 0; j < 4; ++j) v[j] = acc[i][j][rr] + bias[j * 16 + q15];
            float m = fmaxf(fmaxf(v[0], v[1]), fmaxf(v[2], v[3]));
#pragma unroll
            for (int off = 1; off <= 8; off <<= 1) m = fmaxf(m, __shfl_xor(m, off, 64));
            float s = __expf(v[0] - m) + __expf(v[1] - m) + __expf(v[2] - m) + __expf(v[3] - m);
#pragma unroll
            for (int off = 1; off <= 8; off <<= 1) s += __shfl_xor(s, off, 64);
            float ls = m + logf(s);
            int grow = rowBase + wave * 32 + i * 16 + quad * 4 + rr;
            if (grow < M) {
#pragma unroll
                for (int j = 0; j < 4; ++j) {
                    int col = j * 16 + q15;
                    emb[(size_t)grow * OUTDIM + col] = v[j];
                    out[(size_t)grow * OUTDIM + col] = v[j] - ls;
                }
            }
        }
    }
}

// ---------------- launch ----------------

extern "C" void kernel_launch(void* const* d_in, const int* in_sizes, int n_in,
                              void* d_out, int out_size, void* d_ws, size_t ws_size,
                              hipStream_t stream) {
    const float* x   = (const float*)d_in[0];
    const int*   ei  = (const int*)d_in[1];
    const float* W1  = (const float*)d_in[2];
    const float* at_s1 = (const float*)d_in[3];
    const float* at_d1 = (const float*)d_in[4];
    const float* b1  = (const float*)d_in[5];
    const float* W2  = (const float*)d_in[6];
    const float* at_s2 = (const float*)d_in[7];
    const float* at_d2 = (const float*)d_in[8];
    const float* b2  = (const float*)d_in[9];
    const float* g1  = (const float*)d_in[10];
    const float* be1 = (const float*)d_in[11];
    const float* g2  = (const float*)d_in[12];
    const float* be2 = (const float*)d_in[13];
    const float* Wl  = (const float*)d_in[14];
    const float* bl  = (const float*)d_in[15];

    float* out = (float*)d_out;                        // [N, 64] log_softmax
    float* emb = out + (size_t)NNODES * OUTDIM;        // [N, 64] emb

    char* ws = (char*)d_ws;
    size_t off = 0;
    auto alloc = [&](size_t bytes) {
        void* p = ws + off;
        off += (bytes + 255) & ~(size_t)255;
        return p;
    };
    int*   cnt     = (int*)alloc((size_t)NNODES * 4);
    int*   row_off = (int*)alloc((size_t)(NNODES + 1) * 4);
    int*   nxt     = (int*)alloc((size_t)NNODES * 4);
    int*   bsums   = (int*)alloc(64 * 4);
    int*   csr_src = (int*)alloc((size_t)ETOT * 4);
    float* asrc    = (float*)alloc((size_t)NNODES * 4 * 4);
    float* adst    = (float*)alloc((size_t)NNODES * 4 * 4);
    u16*   xhp     = (u16*)alloc((size_t)NNODES * HC * 2);   // permuted bf16 table
    u16*   ag_bf   = (u16*)alloc((size_t)NNODES * HC * 2);   // permuted aggregate
    u16*   w1t     = (u16*)alloc((size_t)HC * INDIM * 2);
    u16*   w2t     = (u16*)alloc((size_t)HC * HC * 2);
    u16*   wlt     = (u16*)alloc((size_t)OUTDIM * HC * 2);
    float* part    = (float*)alloc((size_t)NB * 512 * 4);
    float* bias2   = (float*)alloc(HC * 4);
    float* blp     = (float*)alloc(OUTDIM * 4);

    // ---- 1. fused CSR build + W1 cast (cooperative) ----
    {
        void* a[] = {(void*)&ei, (void*)&cnt, (void*)&row_off, (void*)&nxt,
                     (void*)&bsums, (void*)&csr_src, (void*)&W1, (void*)&w1t};
        hipLaunchCooperativeKernel((void*)csr_build_kernel, dim3(CSR_BLOCKS), dim3(256),
                                   a, 0, stream);
    }

    dim3 gemmGrid(2, (NNODES + 127) / 128);
    const float* nbias = nullptr;
    int ncols1 = HC, ncols2 = OUTDIM;

    // ---- 2-4. Layer 1 ----
    gemm_gat_kernel<true><<<gemmGrid, 256, 0, stream>>>(x, w1t, nullptr, at_s1, at_d1,
                                                        xhp, asrc, adst, NNODES, INDIM);
    aggregate_kernel<<<NNODES / 4, 256, 0, stream>>>(row_off, csr_src, asrc, adst, xhp, b1, ag_bf);
    {
        void* a[] = {(void*)&ag_bf, (void*)&part, (void*)&W2, (void*)&g1, (void*)&be1,
                     (void*)&nbias, (void*)&w2t, (void*)&bias2, (void*)&ncols1};
        hipLaunchCooperativeKernel((void*)statsfold_kernel, dim3(257), dim3(256),
                                   a, 0, stream);
    }

    // ---- 5-7. Layer 2 (BN1 folded into W2/bias2) ----
    gemm_gat_kernel<false><<<gemmGrid, 256, 0, stream>>>(ag_bf, w2t, bias2, at_s2, at_d2,
                                                         xhp, asrc, adst, NNODES, HC);
    aggregate_kernel<<<NNODES / 4, 256, 0, stream>>>(row_off, csr_src, asrc, adst, xhp, b2, ag_bf);
    {
        void* a[] = {(void*)&ag_bf, (void*)&part, (void*)&Wl, (void*)&g2, (void*)&be2,
                     (void*)&bl, (void*)&wlt, (void*)&blp, (void*)&ncols2};
        hipLaunchCooperativeKernel((void*)statsfold_kernel, dim3(257), dim3(256),
                                   a, 0, stream);
    }

    // ---- 8. Final linear (BN2 folded) + log_softmax, fused ----
    final_ls_kernel<<<(NNODES + 127) / 128, 256, 0, stream>>>(ag_bf, wlt, blp, emb, out, NNODES);
}

// Round 6
// 483.433 us; speedup vs baseline: 2.6325x; 2.6325x over previous
//
#include <hip/hip_runtime.h>
#include <cstdint>

#define NNODES 50000
#define NEDGES 800000
#define ETOT   (NEDGES + NNODES)
#define HEADS 4
#define CH 64
#define HC 256
#define INDIM 256
#define OUTDIM 64
#define NEG_SLOPE 0.2f
#define BN_EPS 1e-5f
#define NB 128   // bn_stats partial blocks

typedef unsigned short u16;
typedef unsigned int u32;
typedef __attribute__((ext_vector_type(8))) short short8;
typedef __attribute__((ext_vector_type(8))) unsigned short ushort8v;
typedef __attribute__((ext_vector_type(4))) float floatx4;

__device__ inline float bf2f(u16 u) {
    union { unsigned int i; float f; } c;
    c.i = ((unsigned int)u) << 16;
    return c.f;
}
__device__ inline u16 f2bf(float f) {
    union { float f; unsigned int i; } c;
    c.f = f;
    unsigned int u = c.i + 0x7fff + ((c.i >> 16) & 1);
    return (u16)(u >> 16);
}
// permuted position of logical channel b (within-head 16x4 transpose)
__device__ __host__ inline int pos256(int b) {
    int h = b >> 6, c = b & 63;
    return h * 64 + (c & 15) * 4 + (c >> 4);
}
__device__ inline void async16(u16* lds, const u16* g) {
    __builtin_amdgcn_global_load_lds(
        (const __attribute__((address_space(1))) unsigned int*)g,
        (__attribute__((address_space(3))) unsigned int*)lds,
        16, 0, 0);
}

// ---------------- CSR build (dst-sorted) ----------------

__global__ void hist_kernel(const int* __restrict__ ei, int* __restrict__ cnt) {
    int t = blockIdx.x * blockDim.x + threadIdx.x;
    if (t >= ETOT) return;
    int d = (t < NEDGES) ? ei[NEDGES + t] : (t - NEDGES);
    atomicAdd(&cnt[d], 1);
}

__global__ void scan1_kernel(const int* __restrict__ cnt, int* __restrict__ row_off,
                             int* __restrict__ blockSums) {
    __shared__ int tsum[256];
    const int tid = threadIdx.x;
    const int base = blockIdx.x * 4096 + tid * 16;
    int local[16];
    int run = 0;
#pragma unroll
    for (int i = 0; i < 16; ++i) {
        int idx = base + i;
        int v = (idx < NNODES) ? cnt[idx] : 0;
        local[i] = run;
        run += v;
    }
    tsum[tid] = run;
    __syncthreads();
    for (int d = 1; d < 256; d <<= 1) {
        int v = (tid >= d) ? tsum[tid - d] : 0;
        __syncthreads();
        tsum[tid] += v;
        __syncthreads();
    }
    int excl = (tid == 0) ? 0 : tsum[tid - 1];
#pragma unroll
    for (int i = 0; i < 16; ++i) {
        int idx = base + i;
        if (idx < NNODES) row_off[idx] = excl + local[i];
    }
    if (tid == 0) blockSums[blockIdx.x] = tsum[255];
}

__global__ void scan2_kernel(int* __restrict__ row_off, const int* __restrict__ blockSums,
                             int* __restrict__ nxt) {
    __shared__ int sprefix;
    if (threadIdx.x == 0) {
        int p = 0;
        for (int b = 0; b < (int)blockIdx.x; ++b) p += blockSums[b];
        sprefix = p;
    }
    __syncthreads();
    int prefix = sprefix;
    int base = blockIdx.x * 4096 + threadIdx.x * 16;
#pragma unroll
    for (int i = 0; i < 16; ++i) {
        int idx = base + i;
        if (idx < NNODES) {
            int v = row_off[idx] + prefix;
            row_off[idx] = v;
            nxt[idx] = v;
        }
    }
    if (blockIdx.x == 0 && threadIdx.x == 0) row_off[NNODES] = ETOT;
}

// 4 edges per thread (independent atomic->store chains for MLP), 4B payload.
#define FILL_S (ETOT / 4)   // 212500, exact
__global__ void fill_csr_kernel(const int* __restrict__ ei, int* __restrict__ nxt,
                                int* __restrict__ csr_src) {
    int t = blockIdx.x * blockDim.x + threadIdx.x;
    if (t >= FILL_S) return;
    int s[4], d[4], p[4];
#pragma unroll
    for (int k = 0; k < 4; ++k) {
        int e = t + k * FILL_S;
        if (e < NEDGES) { s[k] = ei[e]; d[k] = ei[NEDGES + e]; }
        else            { s[k] = d[k] = e - NEDGES; }
    }
#pragma unroll
    for (int k = 0; k < 4; ++k) p[k] = atomicAdd(&nxt[d[k]], 1);
#pragma unroll
    for (int k = 0; k < 4; ++k) csr_src[p[k]] = s[k];
}

// ---------------- weight cast: W [K][Ncols] fp32 -> Wt [Ncols][K] bf16 ----------------

__global__ void wcast_kernel(const float* __restrict__ W, u16* __restrict__ Wt,
                             int K, int Ncols) {
    int t = blockIdx.x * blockDim.x + threadIdx.x;
    if (t >= K * Ncols) return;
    int k = t / Ncols, n = t - k * Ncols;
    Wt[n * K + k] = f2bf(W[t]);
}

// ---------------- bf16 MFMA GEMM + fused alpha + permuted bf16 output ----------------
// 8-wave block (512 threads) computes the FULL 128x256 output tile: wave grid
// 2(M) x 4(N); wave's head = wave & 3. A is staged ONCE per block (vs twice in
// the 2-col-block variant) -> halves A HBM/L2 traffic. B panel 256x32/K-step.

template <bool AF32>
__global__ __launch_bounds__(512)
void gemm_gat_kernel(const void* __restrict__ Ap, const u16* __restrict__ Bt,
                     const float* __restrict__ bias,
                     const float* __restrict__ att_s, const float* __restrict__ att_d,
                     u16* __restrict__ xhp, float* __restrict__ asrc,
                     float* __restrict__ adst, int M, int K) {
    __shared__ u16 As[128 * 32];   // 8 KB
    __shared__ u16 Bs[256 * 32];   // 16 KB
    const int tid = threadIdx.x;
    const int wave = tid >> 6, lane = tid & 63;
    const int q15 = lane & 15, quad = lane >> 4;
    const int rowBase = blockIdx.x * 128;
    const int waveM = (wave >> 2) * 64;      // 0 or 64
    const int waveN = (wave & 3) * 64;       // 0,64,128,192
    const int head = wave & 3;

    floatx4 acc[4][4];
    floatx4 zero = {0.f, 0.f, 0.f, 0.f};
#pragma unroll
    for (int i = 0; i < 4; ++i)
#pragma unroll
        for (int j = 0; j < 4; ++j) acc[i][j] = zero;

    for (int kt = 0; kt < K; kt += 32) {
        if constexpr (AF32) {
            // A fp32 -> bf16 via VALU: 512 threads x 8 elems = 128x32
            const float* A32 = (const float*)Ap;
            {
                int r = tid >> 2, c = (tid & 3) * 8;
                int ar = rowBase + r; if (ar >= M) ar = M - 1;
                const float* src = &A32[(size_t)ar * K + kt + c];
                float4 f0 = *(const float4*)src;
                float4 f1 = *(const float4*)(src + 4);
                ushort8v o;
                o[0] = f2bf(f0.x); o[1] = f2bf(f0.y); o[2] = f2bf(f0.z); o[3] = f2bf(f0.w);
                o[4] = f2bf(f1.x); o[5] = f2bf(f1.y); o[6] = f2bf(f1.z); o[7] = f2bf(f1.w);
                *(ushort8v*)&As[r * 32 + c] = o;
            }
        } else {
            // A bf16 via global_load_lds: 512 issues (1/thread)
            const u16* A16 = (const u16*)Ap;
            int e8 = tid;                         // = wave*64 + lane
            int r = e8 >> 2, c = (e8 & 3) * 8;
            int ar = rowBase + r; if (ar >= M) ar = M - 1;
            async16(&As[(wave * 64) * 8], &A16[(size_t)ar * K + kt + c]);
        }
        // B: 256x32 via global_load_lds: 1024 issues (2/thread)
#pragma unroll
        for (int q = 0; q < 2; ++q) {
            int e8 = q * 512 + wave * 64 + lane;
            int r = e8 >> 2, c = (e8 & 3) * 8;    // r = output col 0..255
            async16(&Bs[(q * 512 + wave * 64) * 8], &Bt[(size_t)r * K + kt + c]);
        }
        __syncthreads();

        short8 af[4], bfr[4];
#pragma unroll
        for (int i = 0; i < 4; ++i)
            af[i] = *(const short8*)&As[(waveM + i * 16 + q15) * 32 + quad * 8];
#pragma unroll
        for (int j = 0; j < 4; ++j)
            bfr[j] = *(const short8*)&Bs[(waveN + j * 16 + q15) * 32 + quad * 8];
#pragma unroll
        for (int i = 0; i < 4; ++i)
#pragma unroll
            for (int j = 0; j < 4; ++j)
                acc[i][j] = __builtin_amdgcn_mfma_f32_16x16x32_bf16(af[i], bfr[j], acc[i][j], 0, 0, 0);
        __syncthreads();
    }

    float bv[4], atsv[4], atdv[4];
#pragma unroll
    for (int j = 0; j < 4; ++j) {
        int gcol = waveN + j * 16 + q15;          // == head*CH + j*16 + q15
        bv[j] = bias ? bias[gcol] : 0.f;
        atsv[j] = att_s[gcol];
        atdv[j] = att_d[gcol];
    }
    const int pbase = head * 64 + q15 * 4;

#pragma unroll
    for (int i = 0; i < 4; ++i) {
#pragma unroll
        for (int rr = 0; rr < 4; ++rr) {
            int grow = rowBase + waveM + i * 16 + quad * 4 + rr;
            float v[4];
#pragma unroll
            for (int j = 0; j < 4; ++j) v[j] = acc[i][j][rr] + bv[j];
            float s = v[0] * atsv[0] + v[1] * atsv[1] + v[2] * atsv[2] + v[3] * atsv[3];
            float d = v[0] * atdv[0] + v[1] * atdv[1] + v[2] * atdv[2] + v[3] * atdv[3];
#pragma unroll
            for (int off = 1; off <= 8; off <<= 1) {
                s += __shfl_xor(s, off, 64);
                d += __shfl_xor(d, off, 64);
            }
            ushort4 o;
            o.x = f2bf(v[0]); o.y = f2bf(v[1]); o.z = f2bf(v[2]); o.w = f2bf(v[3]);
            if (grow < M) {
                *(ushort4*)&xhp[(size_t)grow * HC + pbase] = o;
                if (q15 == 0) {
                    asrc[grow * 4 + head] = s;
                    adst[grow * 4 + head] = d;
                }
            }
        }
    }
}

// ---------------- fused softmax+aggregate over permuted bf16 table ----------------
// 1 wave = 1 dst node (proven structure; at the random-512B-gather fabric
// ceiling ~3.7 TB/s). Per 64-edge batch: per-wave LDS table of exp-weights +
// src; main loop reads 2 edges per dwordx4 gather, unrolled to 8 edges.

__global__ __launch_bounds__(256)
void aggregate_kernel(const int* __restrict__ row_off, const int* __restrict__ csr_src,
                      const float* __restrict__ asrc, const float* __restrict__ adst,
                      const u16* __restrict__ xhp, const float* __restrict__ bias,
                      u16* __restrict__ out) {
    __shared__ int eb[4][512];          // per wave: 64 edges x {w0..w3 (f32), sv, pad3}
    const int g = threadIdx.x >> 6;
    const int lane = threadIdx.x & 63;
    const int d = blockIdx.x * 4 + g;
    const int eh = lane >> 5;            // which edge of a pair this lane serves
    const int L = lane & 31;
    const int h = L >> 3;                // head
    const int g8 = L & 7;                // 8-position group within head
    const u32 pb = (u32)(h * 128 + g8 * 16);   // byte offset within row (16B aligned)
    int* my = &eb[g][0];

    const int start = row_off[d], end = row_off[d + 1];
    const float4 ad4 = *(const float4*)&adst[d * 4];   // wave-uniform
    float acc[8] = {0.f, 0.f, 0.f, 0.f, 0.f, 0.f, 0.f, 0.f};
    float den = 0.f;

#define ACC4(W, Q, J0) { u32 dw_ = (u32)(Q); \
        acc[J0]     += (W) * __int_as_float(dw_ << 16); \
        acc[(J0)+1] += (W) * __int_as_float(dw_ & 0xffff0000u); }

    for (int base = start; base < end; base += 64) {
        const int cnt = min(64, end - base);
        int4 pack = {0, 0, 0, 0};
        int svv = 0;
        if (lane < cnt) {
            svv = csr_src[base + lane];
            float4 as4 = *(const float4*)&asrc[svv * 4];
            float e0 = as4.x + ad4.x; e0 = e0 > 0.f ? e0 : NEG_SLOPE * e0;
            float e1 = as4.y + ad4.y; e1 = e1 > 0.f ? e1 : NEG_SLOPE * e1;
            float e2 = as4.z + ad4.z; e2 = e2 > 0.f ? e2 : NEG_SLOPE * e2;
            float e3 = as4.w + ad4.w; e3 = e3 > 0.f ? e3 : NEG_SLOPE * e3;
            pack.x = __float_as_int(__expf(e0));
            pack.y = __float_as_int(__expf(e1));
            pack.z = __float_as_int(__expf(e2));
            pack.w = __float_as_int(__expf(e3));
        }
        *(int4*)&my[lane * 8] = pack;    // zeroed beyond cnt -> safe padding
        my[lane * 8 + 4] = svv;
        // cross-lane LDS RAW within the wave: drain before pair reads.
        asm volatile("s_waitcnt lgkmcnt(0)" ::: "memory");
        __builtin_amdgcn_sched_barrier(0);

        const int cntp = (cnt + 1) & ~1;  // pad to even; padded edge has w=0
        int k = 0;
        for (; k + 7 < cntp; k += 8) {
            float wv[4]; int sa[4];
#pragma unroll
            for (int p = 0; p < 4; ++p) {
                int idx = (k + 2 * p + eh) * 8;
                wv[p] = __int_as_float(my[idx + h]);
                sa[p] = my[idx + 4];
            }
            int4 gv[4];
#pragma unroll
            for (int p = 0; p < 4; ++p) {
                u32 off = ((u32)sa[p] << 9) + pb;
                gv[p] = *(const int4*)((const char*)xhp + off);
            }
#pragma unroll
            for (int p = 0; p < 4; ++p) {
                float w = wv[p];
                den += w;
                ACC4(w, gv[p].x, 0); ACC4(w, gv[p].y, 2);
                ACC4(w, gv[p].z, 4); ACC4(w, gv[p].w, 6);
            }
        }
        for (; k < cntp; k += 2) {
            int idx = (k + eh) * 8;
            float w = __int_as_float(my[idx + h]);
            int s = my[idx + 4];
            u32 off = ((u32)s << 9) + pb;
            int4 gvv = *(const int4*)((const char*)xhp + off);
            den += w;
            ACC4(w, gvv.x, 0); ACC4(w, gvv.y, 2);
            ACC4(w, gvv.z, 4); ACC4(w, gvv.w, 6);
        }
    }
#undef ACC4

#pragma unroll
    for (int i = 0; i < 8; ++i) acc[i] += __shfl_xor(acc[i], 32, 64);
    den += __shfl_xor(den, 32, 64);

    if (eh == 0) {
        float inv = 1.f / (den + 1e-16f);
        const int cb = h * 64 + g8 * 2;   // logical channel base for j=0
        ushort8v o;
#pragma unroll
        for (int j = 0; j < 8; ++j)
            o[j] = f2bf(acc[j] * inv + bias[cb + (j >> 2) + (j & 3) * 16]);
        *(ushort8v*)&out[(size_t)d * HC + h * 64 + g8 * 8] = o;   // permuted, coalesced
    }
}

// ---------------- BatchNorm stats over permuted buffer (positional) ----------------

__global__ __launch_bounds__(256)
void bn_stats_kernel(const u16* __restrict__ x, float* __restrict__ part) {
    const int tid = threadIdx.x;
    float s[8] = {}, s2[8] = {};
    const size_t total = (size_t)NNODES * HC;
    const size_t stride = (size_t)NB * 256 * 8;
    for (size_t f = ((size_t)blockIdx.x * 256 + tid) * 8; f < total; f += stride) {
        ushort8v v = *(const ushort8v*)&x[f];
#pragma unroll
        for (int i = 0; i < 8; ++i) {
            float t = bf2f(v[i]);
            s[i] += t;
            s2[i] += t * t;
        }
    }
#pragma unroll
    for (int i = 0; i < 8; ++i) {
        s[i] += __shfl_xor(s[i], 32, 64);
        s2[i] += __shfl_xor(s2[i], 32, 64);
    }
    __shared__ float red[4][512];
    const int wave = tid >> 6, lane = tid & 63;
    if (lane < 32) {
#pragma unroll
        for (int i = 0; i < 8; ++i) {
            red[wave][lane * 8 + i] = s[i];
            red[wave][256 + lane * 8 + i] = s2[i];
        }
    }
    __syncthreads();
    for (int j = tid; j < 512; j += 256)
        part[(size_t)blockIdx.x * 512 + j] = red[0][j] + red[1][j] + red[2][j] + red[3][j];
}

// ---------------- BN fold (permutation-aware) ----------------

__global__ __launch_bounds__(256)
void fold_kernel(const float* __restrict__ W, const float* __restrict__ part,
                 const float* __restrict__ g, const float* __restrict__ beta,
                 const float* __restrict__ baseBias,
                 u16* __restrict__ Wt, float* __restrict__ biasOut, int Ncols) {
    __shared__ float sh[256];
    __shared__ float stat2[2];
    const int b = blockIdx.x;
    const int tid = threadIdx.x;
    if (b < 256) {
        const int p = pos256(b);
        const int wave = tid >> 6, lane = tid & 63;
        if (wave < 2) {
            int off = wave * 256;
            float v = part[(size_t)lane * 512 + off + p] + part[(size_t)(lane + 64) * 512 + off + p];
#pragma unroll
            for (int o = 1; o <= 32; o <<= 1) v += __shfl_xor(v, o, 64);
            if (lane == 0) stat2[wave] = v;
        }
        __syncthreads();
        float mu = stat2[0] * (1.f / NNODES);
        float var = stat2[1] * (1.f / NNODES) - mu * mu;
        float rg = rsqrtf(var + BN_EPS) * g[b];
        for (int n = tid; n < Ncols; n += 256)
            Wt[n * 256 + p] = f2bf(W[b * Ncols + n] * rg);
    } else {
        const int p = pos256(tid);
        float sum = 0.f, sq = 0.f;
        for (int k = 0; k < NB; ++k) {
            sum += part[(size_t)k * 512 + p];
            sq += part[(size_t)k * 512 + 256 + p];
        }
        float mu = sum * (1.f / NNODES);
        float var = sq * (1.f / NNODES) - mu * mu;
        float rg = rsqrtf(var + BN_EPS) * g[tid];
        sh[tid] = beta[tid] - mu * rg;
        __syncthreads();
        if (tid < Ncols) {
            float acc = baseBias ? baseBias[tid] : 0.f;
            for (int k = 0; k < 256; ++k) acc += sh[k] * W[k * Ncols + tid];
            biasOut[tid] = acc;
        }
    }
}

// ---------------- fused final GEMM (M x 64, K=256) + bias + log_softmax ----------------

__global__ __launch_bounds__(256)
void final_ls_kernel(const u16* __restrict__ A, const u16* __restrict__ Bt,
                     const float* __restrict__ bias,
                     float* __restrict__ emb, float* __restrict__ out, int M) {
    __shared__ u16 As[128 * 32];
    __shared__ u16 Bs[64 * 32];
    const int tid = threadIdx.x;
    const int wave = tid >> 6, lane = tid & 63;
    const int q15 = lane & 15, quad = lane >> 4;
    const int rowBase = blockIdx.x * 128;

    floatx4 acc[2][4];
    floatx4 zero = {0.f, 0.f, 0.f, 0.f};
#pragma unroll
    for (int i = 0; i < 2; ++i)
#pragma unroll
        for (int j = 0; j < 4; ++j) acc[i][j] = zero;

    for (int kt = 0; kt < 256; kt += 32) {
#pragma unroll
        for (int rnd = 0; rnd < 2; ++rnd) {
            int slot = rnd * 256 + wave * 64 + lane;
            int r = slot >> 2;
            int c = (slot & 3) * 8;
            int ar = rowBase + r; if (ar >= M) ar = M - 1;
            async16(&As[(rnd * 256 + wave * 64) * 8], &A[(size_t)ar * 256 + kt + c]);
        }
        {
            int slot = wave * 64 + lane;
            int r = slot >> 2;
            int c = (slot & 3) * 8;
            async16(&Bs[(wave * 64) * 8], &Bt[(size_t)r * 256 + kt + c]);
        }
        __syncthreads();

        short8 af[2], bfr[4];
#pragma unroll
        for (int i = 0; i < 2; ++i)
            af[i] = *(const short8*)&As[(wave * 32 + i * 16 + q15) * 32 + quad * 8];
#pragma unroll
        for (int j = 0; j < 4; ++j)
            bfr[j] = *(const short8*)&Bs[(j * 16 + q15) * 32 + quad * 8];
#pragma unroll
        for (int i = 0; i < 2; ++i)
#pragma unroll
            for (int j = 0; j < 4; ++j)
                acc[i][j] = __builtin_amdgcn_mfma_f32_16x16x32_bf16(af[i], bfr[j], acc[i][j], 0, 0, 0);
        __syncthreads();
    }

#pragma unroll
    for (int i = 0; i < 2; ++i) {
#pragma unroll
        for (int rr = 0; rr < 4; ++rr) {
            float v[4];
#pragma unroll
            for (int j = 0; j < 4; ++j) v[j] = acc[i][j][rr] + bias[j * 16 + q15];
            float m = fmaxf(fmaxf(v[0], v[1]), fmaxf(v[2], v[3]));
#pragma unroll
            for (int off = 1; off <= 8; off <<= 1) m = fmaxf(m, __shfl_xor(m, off, 64));
            float s = __expf(v[0] - m) + __expf(v[1] - m) + __expf(v[2] - m) + __expf(v[3] - m);
#pragma unroll
            for (int off = 1; off <= 8; off <<= 1) s += __shfl_xor(s, off, 64);
            float ls = m + logf(s);
            int grow = rowBase + wave * 32 + i * 16 + quad * 4 + rr;
            if (grow < M) {
#pragma unroll
                for (int j = 0; j < 4; ++j) {
                    int col = j * 16 + q15;
                    emb[(size_t)grow * OUTDIM + col] = v[j];
                    out[(size_t)grow * OUTDIM + col] = v[j] - ls;
                }
            }
        }
    }
}

// ---------------- launch ----------------

extern "C" void kernel_launch(void* const* d_in, const int* in_sizes, int n_in,
                              void* d_out, int out_size, void* d_ws, size_t ws_size,
                              hipStream_t stream) {
    const float* x   = (const float*)d_in[0];
    const int*   ei  = (const int*)d_in[1];
    const float* W1  = (const float*)d_in[2];
    const float* at_s1 = (const float*)d_in[3];
    const float* at_d1 = (const float*)d_in[4];
    const float* b1  = (const float*)d_in[5];
    const float* W2  = (const float*)d_in[6];
    const float* at_s2 = (const float*)d_in[7];
    const float* at_d2 = (const float*)d_in[8];
    const float* b2  = (const float*)d_in[9];
    const float* g1  = (const float*)d_in[10];
    const float* be1 = (const float*)d_in[11];
    const float* g2  = (const float*)d_in[12];
    const float* be2 = (const float*)d_in[13];
    const float* Wl  = (const float*)d_in[14];
    const float* bl  = (const float*)d_in[15];

    float* out = (float*)d_out;                        // [N, 64] log_softmax
    float* emb = out + (size_t)NNODES * OUTDIM;        // [N, 64] emb

    char* ws = (char*)d_ws;
    size_t off = 0;
    auto alloc = [&](size_t bytes) {
        void* p = ws + off;
        off += (bytes + 255) & ~(size_t)255;
        return p;
    };
    int*   cnt     = (int*)alloc((size_t)NNODES * 4);
    int*   row_off = (int*)alloc((size_t)(NNODES + 1) * 4);
    int*   nxt     = (int*)alloc((size_t)NNODES * 4);
    int*   bsums   = (int*)alloc(64 * 4);
    int*   csr_src = (int*)alloc((size_t)ETOT * 4);
    float* asrc    = (float*)alloc((size_t)NNODES * 4 * 4);
    float* adst    = (float*)alloc((size_t)NNODES * 4 * 4);
    u16*   xhp     = (u16*)alloc((size_t)NNODES * HC * 2);   // permuted bf16 table
    u16*   ag_bf   = (u16*)alloc((size_t)NNODES * HC * 2);   // permuted aggregate
    u16*   w1t     = (u16*)alloc((size_t)HC * INDIM * 2);
    u16*   w2t     = (u16*)alloc((size_t)HC * HC * 2);
    u16*   wlt     = (u16*)alloc((size_t)OUTDIM * HC * 2);
    float* part    = (float*)alloc((size_t)NB * 512 * 4);
    float* bias2   = (float*)alloc(HC * 4);
    float* blp     = (float*)alloc(OUTDIM * 4);

    const int scanBlocks = (NNODES + 4095) / 4096;
    const int eBlocks = (ETOT + 255) / 256;

    // ---- CSR build ----
    hipMemsetAsync(cnt, 0, (size_t)NNODES * 4, stream);
    hist_kernel<<<eBlocks, 256, 0, stream>>>(ei, cnt);
    scan1_kernel<<<scanBlocks, 256, 0, stream>>>(cnt, row_off, bsums);
    scan2_kernel<<<scanBlocks, 256, 0, stream>>>(row_off, bsums, nxt);
    fill_csr_kernel<<<(FILL_S + 255) / 256, 256, 0, stream>>>(ei, nxt, csr_src);

    // ---- weight cast (layer-1 only; layer-2/final fold their own) ----
    wcast_kernel<<<(INDIM * HC + 255) / 256, 256, 0, stream>>>(W1, w1t, INDIM, HC);

    const int gemmBlocks = (NNODES + 127) / 128;

    // ---- Layer 1 (fp32-A gemm + fused alpha + permuted bf16 table) ----
    gemm_gat_kernel<true><<<gemmBlocks, 512, 0, stream>>>(x, w1t, nullptr, at_s1, at_d1,
                                                          xhp, asrc, adst, NNODES, INDIM);
    aggregate_kernel<<<NNODES / 4, 256, 0, stream>>>(row_off, csr_src, asrc, adst, xhp, b1, ag_bf);
    bn_stats_kernel<<<NB, 256, 0, stream>>>(ag_bf, part);
    fold_kernel<<<257, 256, 0, stream>>>(W2, part, g1, be1, nullptr, w2t, bias2, HC);

    // ---- Layer 2 (BN1 folded into W2/bias2; A permuted, Wt K-permuted to match) ----
    gemm_gat_kernel<false><<<gemmBlocks, 512, 0, stream>>>(ag_bf, w2t, bias2, at_s2, at_d2,
                                                           xhp, asrc, adst, NNODES, HC);
    aggregate_kernel<<<NNODES / 4, 256, 0, stream>>>(row_off, csr_src, asrc, adst, xhp, b2, ag_bf);
    bn_stats_kernel<<<NB, 256, 0, stream>>>(ag_bf, part);
    fold_kernel<<<257, 256, 0, stream>>>(Wl, part, g2, be2, bl, wlt, blp, OUTDIM);

    // ---- Final linear (BN2 folded) + log_softmax, fused ----
    final_ls_kernel<<<(NNODES + 127) / 128, 256, 0, stream>>>(ag_bf, wlt, blp, emb, out, NNODES);
}